// Round 3
// baseline (542.612 us; speedup 1.0000x reference)
//
#include <hip/hip_runtime.h>

// TxModel: B=16384, K=64 tokens, DIN=49, D=16, NH=2, HD=8, FF=32
// Block = 256 threads = 4 waves, one batch element per block.
// Wave w owns M-tile w (tokens w*16..w*16+15). All row buffers are
// wave-private (wave w writes AND reads only its own 16 rows) -> only 3
// block-wide barriers (staging, K/V publish, final reduce).
// C-layout (16x16x32 mfma): lane (g=lane>>4, c=lane&15) reg r -> (row=g*4+r, col=c).
// A-layout: lane holds row c, k = g*8+j. Per-token math (bias, softmax 1/l,
// LN, head) done in C-layout via 16-lane shuffle butterflies.

#define XR   0       // [64][72] bf16: x rows (K=49 pad 64) -> P rows (64x64)
#define XRS  72
#define HR   4608    // [64][40] bf16: h/q/ctx/hln/ff rows; cols 16..31 zeroed
#define HRS  40
#define KR   7168    // [64][40] bf16: k rows (shared across waves)
#define KRS  40
#define VTB  9728    // [16][72] bf16: v transposed [dim][token] (shared)
#define VTS  72
#define RED  10880   // 4 floats: per-wave head partials
#define SMTOT 10888  // shorts = 21776 B

typedef __bf16 v8bf __attribute__((ext_vector_type(8)));
typedef float  v4f  __attribute__((ext_vector_type(4)));

// Compiler-level ordering fence: stops LDS stores being hoisted above the
// type-punned v8bf loads that follow (HW DS pipe is in-order per wave).
#define LDS_ORDER() __asm__ volatile("" ::: "memory")

static __device__ __forceinline__ short f2bs(float f) {
    __bf16 h = (__bf16)f;
    return __builtin_bit_cast(short, h);
}
#define MFMA(a,b,c) __builtin_amdgcn_mfma_f32_16x16x32_bf16((a),(b),(c),0,0,0)

__global__ __launch_bounds__(256, 4)
void tx_mfma4(const float* __restrict__ x,
              const float* __restrict__ proj_w, const float* __restrict__ proj_b,
              const float* __restrict__ pos,
              const float* __restrict__ in_proj_w, const float* __restrict__ in_proj_b,
              const float* __restrict__ out_w, const float* __restrict__ out_b,
              const float* __restrict__ ln1_g, const float* __restrict__ ln1_b,
              const float* __restrict__ lin1_w, const float* __restrict__ lin1_b,
              const float* __restrict__ lin2_w, const float* __restrict__ lin2_b,
              const float* __restrict__ ln2_g, const float* __restrict__ ln2_b,
              const float* __restrict__ head_w, const float* __restrict__ head_b,
              float* __restrict__ out)
{
    __shared__ __align__(16) short sm[SMTOT];
    const int tid   = threadIdx.x;
    const int w     = tid >> 6;          // wave id = M-tile
    const int lane  = tid & 63;
    const int g     = lane >> 4;
    const int c     = lane & 15;
    const int b     = blockIdx.x;
    const int myrow = w*16 + c;          // A-frag row this lane reads
    const int tok0  = w*16 + g*4;        // first of 4 tokens in C-layout regs

    v8bf zfrag;
    #pragma unroll
    for (int j = 0; j < 8; ++j) zfrag[j] = (__bf16)0.f;

    // ---- stage x -> XR bf16 rows, coalesced float4 over 256 threads ----
    const float4* xb4 = (const float4*)(x + (size_t)b * 3136);
    #pragma unroll
    for (int i = 0; i < 3; ++i) {
        int idx = tid + i*256;
        float4 v = xb4[idx];
        float vv[4] = {v.x, v.y, v.z, v.w};
        int flat = idx*4;
        #pragma unroll
        for (int e = 0; e < 4; ++e) {
            int f = flat + e, row = f / 49, col = f - row*49;
            sm[XR + row*XRS + col] = f2bs(vv[e]);
        }
    }
    if (tid < 16) {
        int idx = 768 + tid;
        float4 v = xb4[idx];
        float vv[4] = {v.x, v.y, v.z, v.w};
        int flat = idx*4;
        #pragma unroll
        for (int e = 0; e < 4; ++e) {
            int f = flat + e, row = f / 49, col = f - row*49;
            sm[XR + row*XRS + col] = f2bs(vv[e]);
        }
    }
    // pad x cols 49..63 on my wave's rows (NaN guard for A-frags)
    #pragma unroll
    for (int j = 0; j < 4; ++j) {
        int col = 49 + g*4 + j;
        if (col < 64) sm[XR + myrow*XRS + col] = 0;
    }
    // zero HR cols 16..31 on my wave's rows (K=16 GEMMs padded to 32)
    *(unsigned long long*)&sm[HR + myrow*HRS + 16 + g*4] = 0ull;
    __syncthreads();

    // ---- proj: h = x @ proj_w^T (+ proj_b + pos), kept fp32 in C-layout ----
    v4f hC;
    {
        v8bf Bp0, Bp1;
        #pragma unroll
        for (int j = 0; j < 8; ++j) {
            int k1 = 32 + g*8 + j;
            Bp0[j] = (__bf16)proj_w[c*49 + g*8 + j];
            Bp1[j] = (k1 < 49) ? (__bf16)proj_w[c*49 + k1] : (__bf16)0.f;
        }
        v8bf a0 = *(const v8bf*)&sm[XR + myrow*XRS + g*8];
        v8bf a1 = *(const v8bf*)&sm[XR + myrow*XRS + 32 + g*8];
        v4f z = {0.f, 0.f, 0.f, 0.f};
        hC = MFMA(a0, Bp0, z);
        hC = MFMA(a1, Bp1, hC);
    }
    {
        float pb = proj_b[c];
        #pragma unroll
        for (int r = 0; r < 4; ++r) hC[r] += pb + pos[(tok0 + r)*16 + c];
        #pragma unroll
        for (int r = 0; r < 4; ++r) sm[HR + (tok0 + r)*HRS + c] = f2bs(hC[r]);
    }
    LDS_ORDER();

    // ---- qkv = h @ in_proj_w^T + b ----
    {
        v8bf Bq0, Bq1, Bq2;
        #pragma unroll
        for (int j = 0; j < 8; ++j) {
            int k = g*8 + j;
            bool ok = k < 16;
            Bq0[j] = ok ? (__bf16)in_proj_w[c*16 + k]        : (__bf16)0.f;
            Bq1[j] = ok ? (__bf16)in_proj_w[(16 + c)*16 + k] : (__bf16)0.f;
            Bq2[j] = ok ? (__bf16)in_proj_w[(32 + c)*16 + k] : (__bf16)0.f;
        }
        v8bf a = *(const v8bf*)&sm[HR + myrow*HRS + g*8];
        v4f z = {0.f, 0.f, 0.f, 0.f};
        v4f qC = MFMA(a, Bq0, z);
        v4f kC = MFMA(a, Bq1, z);
        v4f vC = MFMA(a, Bq2, z);
        float bq = in_proj_b[c], bk = in_proj_b[16 + c], bv = in_proj_b[32 + c];
        #pragma unroll
        for (int r = 0; r < 4; ++r) {
            int tok = tok0 + r;
            sm[HR + tok*HRS + c]   = f2bs(qC[r] + bq);   // q (overwrites h rows; values depend on a -> ordered)
            sm[KR + tok*KRS + c]   = f2bs(kC[r] + bk);   // shared
            sm[VTB + c*VTS + tok]  = f2bs(vC[r] + bv);   // shared, transposed
        }
    }
    __syncthreads();

    // ---- attention: per head, scores->exp->P (private rows) -> PV ----
    v4f ctxC0, ctxC1;
    {
        v8bf aq = *(const v8bf*)&sm[HR + myrow*HRS + g*8];  // cols 16..31 are zero
        const float SC = 0.510069729f;   // log2(e)/sqrt(8); scores<<1 so no max-sub
        #pragma unroll
        for (int hh = 0; hh < 2; ++hh) {
            v4f sC[4];
            #pragma unroll
            for (int tj = 0; tj < 4; ++tj) {
                v8bf bk = zfrag;
                if (g == hh) bk = *(const v8bf*)&sm[KR + (tj*16 + c)*KRS + g*8];
                v4f z = {0.f, 0.f, 0.f, 0.f};
                sC[tj] = MFMA(aq, bk, z);
            }
            #pragma unroll
            for (int tj = 0; tj < 4; ++tj)
                #pragma unroll
                for (int r = 0; r < 4; ++r)
                    sm[XR + (tok0 + r)*XRS + tj*16 + c] = f2bs(exp2f(sC[tj][r] * SC));
            // B-frags for PV: v dims for this head + a ones-column giving row-sum l
            v8bf bv0 = zfrag, bv1 = zfrag;
            bool act  = (hh == 0) ? (c < 8) : (c >= 8);
            int  onec = (hh == 0) ? 8 : 7;
            if (act) {
                bv0 = *(const v8bf*)&sm[VTB + c*VTS + g*8];
                bv1 = *(const v8bf*)&sm[VTB + c*VTS + 32 + g*8];
            } else if (c == onec) {
                #pragma unroll
                for (int j = 0; j < 8; ++j) { bv0[j] = (__bf16)1.f; bv1[j] = (__bf16)1.f; }
            }
            LDS_ORDER();
            v4f acc = {0.f, 0.f, 0.f, 0.f};
            acc = MFMA(*(const v8bf*)&sm[XR + myrow*XRS + g*8],      bv0, acc);
            acc = MFMA(*(const v8bf*)&sm[XR + myrow*XRS + 32 + g*8], bv1, acc);
            if (hh) ctxC1 = acc; else ctxC0 = acc;
        }
    }

    // ---- softmax normalize (l broadcast via shfl) + ctx scatter ----
    {
        int src0 = (lane & 48) | 8;   // lane holding l0 for my rows
        int src1 = (lane & 48) | 7;   // lane holding l1
        #pragma unroll
        for (int r = 0; r < 4; ++r) {
            float l0 = __shfl(ctxC0[r], src0, 64);
            float l1 = __shfl(ctxC1[r], src1, 64);
            float val = (c < 8) ? (ctxC0[r] / l0) : (ctxC1[r] / l1);
            sm[HR + (tok0 + r)*HRS + c] = f2bs(val);
        }
    }
    LDS_ORDER();

    // ---- out-proj + residual + LN1 (C-layout, 16-lane butterflies) ----
    v4f hln;
    {
        v8bf Bo;
        #pragma unroll
        for (int j = 0; j < 8; ++j) {
            int k = g*8 + j;
            Bo[j] = (k < 16) ? (__bf16)out_w[c*16 + k] : (__bf16)0.f;
        }
        v8bf a = *(const v8bf*)&sm[HR + myrow*HRS + g*8];
        v4f z = {0.f, 0.f, 0.f, 0.f};
        v4f oC = MFMA(a, Bo, z);
        float ob = out_b[c];
        v4f hn;
        #pragma unroll
        for (int r = 0; r < 4; ++r) hn[r] = hC[r] + oC[r] + ob;
        v4f s = hn;
        #pragma unroll
        for (int m = 1; m < 16; m <<= 1)
            #pragma unroll
            for (int r = 0; r < 4; ++r) s[r] += __shfl_xor(s[r], m, 64);
        v4f t, vs;
        #pragma unroll
        for (int r = 0; r < 4; ++r) { t[r] = hn[r] - s[r]*0.0625f; vs[r] = t[r]*t[r]; }
        #pragma unroll
        for (int m = 1; m < 16; m <<= 1)
            #pragma unroll
            for (int r = 0; r < 4; ++r) vs[r] += __shfl_xor(vs[r], m, 64);
        float g1 = ln1_g[c], b1 = ln1_b[c];
        #pragma unroll
        for (int r = 0; r < 4; ++r) {
            float is = rsqrtf(vs[r]*0.0625f + 1e-5f);
            hln[r] = t[r]*is*g1 + b1;
            sm[HR + (tok0 + r)*HRS + c] = f2bs(hln[r]);
        }
    }
    LDS_ORDER();

    // ---- FFN: lin1(+bias,relu) -> lin2 (K=32) ----
    v4f o2;
    {
        v8bf Bl10, Bl11, Bl2;
        #pragma unroll
        for (int j = 0; j < 8; ++j) {
            int k = g*8 + j;
            bool ok = k < 16;
            Bl10[j] = ok ? (__bf16)lin1_w[c*16 + k]        : (__bf16)0.f;
            Bl11[j] = ok ? (__bf16)lin1_w[(16 + c)*16 + k] : (__bf16)0.f;
            Bl2[j]  = (__bf16)lin2_w[c*32 + g*8 + j];
        }
        v8bf a = *(const v8bf*)&sm[HR + myrow*HRS + g*8];
        v4f z = {0.f, 0.f, 0.f, 0.f};
        v4f f0 = MFMA(a, Bl10, z);
        v4f f1 = MFMA(a, Bl11, z);
        float lb0 = lin1_b[c], lb1 = lin1_b[16 + c];
        #pragma unroll
        for (int r = 0; r < 4; ++r) {
            int tok = tok0 + r;
            sm[HR + tok*HRS + c]      = f2bs(fmaxf(f0[r] + lb0, 0.f));
            sm[HR + tok*HRS + 16 + c] = f2bs(fmaxf(f1[r] + lb1, 0.f));
        }
        LDS_ORDER();
        v8bf a2 = *(const v8bf*)&sm[HR + myrow*HRS + g*8];  // K=32 exact
        o2 = MFMA(a2, Bl2, z);
    }

    // ---- +lin2_b, residual, LN2, head dot; wave reduce; cross-wave sum ----
    float part = 0.f;
    {
        float lb2 = lin2_b[c];
        v4f hn;
        #pragma unroll
        for (int r = 0; r < 4; ++r) hn[r] = hln[r] + o2[r] + lb2;
        v4f s = hn;
        #pragma unroll
        for (int m = 1; m < 16; m <<= 1)
            #pragma unroll
            for (int r = 0; r < 4; ++r) s[r] += __shfl_xor(s[r], m, 64);
        v4f t, vs;
        #pragma unroll
        for (int r = 0; r < 4; ++r) { t[r] = hn[r] - s[r]*0.0625f; vs[r] = t[r]*t[r]; }
        #pragma unroll
        for (int m = 1; m < 16; m <<= 1)
            #pragma unroll
            for (int r = 0; r < 4; ++r) vs[r] += __shfl_xor(vs[r], m, 64);
        float g2 = ln2_g[c], b2 = ln2_b[c], hw = head_w[c];
        #pragma unroll
        for (int r = 0; r < 4; ++r) {
            float is = rsqrtf(vs[r]*0.0625f + 1e-5f);
            float h3 = t[r]*is*g2 + b2;
            part = fmaf(h3, hw, part);
        }
    }
    #pragma unroll
    for (int m = 1; m < 64; m <<= 1) part += __shfl_xor(part, m, 64);
    float* fred = (float*)&sm[RED];
    if (lane == 0) fred[w] = part;
    __syncthreads();
    if (tid == 0)
        out[b] = (fred[0] + fred[1] + fred[2] + fred[3]) * (1.f/64.f) + head_b[0];
}

extern "C" void kernel_launch(void* const* d_in, const int* in_sizes, int n_in,
                              void* d_out, int out_size, void* d_ws, size_t ws_size,
                              hipStream_t stream) {
    const float* x         = (const float*)d_in[0];
    const float* proj_w    = (const float*)d_in[1];
    const float* proj_b    = (const float*)d_in[2];
    const float* pos       = (const float*)d_in[3];
    const float* in_proj_w = (const float*)d_in[4];
    const float* in_proj_b = (const float*)d_in[5];
    const float* out_w     = (const float*)d_in[6];
    const float* out_b     = (const float*)d_in[7];
    const float* ln1_g     = (const float*)d_in[8];
    const float* ln1_b     = (const float*)d_in[9];
    const float* lin1_w    = (const float*)d_in[10];
    const float* lin1_b    = (const float*)d_in[11];
    const float* lin2_w    = (const float*)d_in[12];
    const float* lin2_b    = (const float*)d_in[13];
    const float* ln2_g     = (const float*)d_in[14];
    const float* ln2_b     = (const float*)d_in[15];
    const float* head_w    = (const float*)d_in[16];
    const float* head_b    = (const float*)d_in[17];

    tx_mfma4<<<16384, 256, 0, stream>>>(
        x, proj_w, proj_b, pos, in_proj_w, in_proj_b, out_w, out_b,
        ln1_g, ln1_b, lin1_w, lin1_b, lin2_w, lin2_b, ln2_g, ln2_b,
        head_w, head_b, (float*)d_out);
}

// Round 4
// 371.873 us; speedup vs baseline: 1.4591x; 1.4591x over previous
//
#include <hip/hip_runtime.h>

// TxModel: B=16384, K=64 tokens, DIN=49, D=16, NH=2, HD=8, FF=32
// Block = 256 threads = 4 waves, one batch element; wave w owns M-tile w.
// R4: (1) prologue kernel pre-bakes frag-ready weights/biases into d_ws so the
// main kernel does ~16 coalesced VMEM loads instead of ~72 scattered gathers
// per wave; (2) XOR block swizzle on XR kills 4-way P-scatter bank conflicts.

#define XR   0       // [64][72] bf16, XOR-block-swizzled: x rows -> P rows
#define XRS  72
#define HR   4608    // [64][40] bf16: h/q/ctx/hln/ff rows; cols 16..31 zeroed
#define HRS  40
#define KR   7168    // [64][40] bf16: k rows (shared)
#define KRS  40
#define VTB  9728    // [16][72] bf16: v transposed [dim][token] (shared)
#define VTS  72
#define RED  10880   // 4 floats
#define SMTOT 10888  // shorts = 21776 B -> 7 blocks/CU

// ws layout (floats): [0,2304) 9 weight B-frags (v8bf: frag*64+lane)
//                     [2304,3328) hbias [w][r][lane] = proj_b[c]+pos[tok][c]
//                     [3328,3584) epil  [c][16]
#define WS_HB   2304
#define WS_EP   3328

typedef __bf16 v8bf __attribute__((ext_vector_type(8)));
typedef float  v4f  __attribute__((ext_vector_type(4)));

#define LDS_ORDER() __asm__ volatile("" ::: "memory")

static __device__ __forceinline__ short f2bs(float f) {
    __bf16 h = (__bf16)f;
    return __builtin_bit_cast(short, h);
}
#define MFMA(a,b,c) __builtin_amdgcn_mfma_f32_16x16x32_bf16((a),(b),(c),0,0,0)

__global__ __launch_bounds__(64)
void tx_prep(const float* __restrict__ proj_w, const float* __restrict__ proj_b,
             const float* __restrict__ pos,
             const float* __restrict__ in_proj_w, const float* __restrict__ in_proj_b,
             const float* __restrict__ out_w, const float* __restrict__ out_b,
             const float* __restrict__ ln1_g, const float* __restrict__ ln1_b,
             const float* __restrict__ lin1_w, const float* __restrict__ lin1_b,
             const float* __restrict__ lin2_w, const float* __restrict__ lin2_b,
             const float* __restrict__ ln2_g, const float* __restrict__ ln2_b,
             const float* __restrict__ head_w, float* __restrict__ ws)
{
    const int lane = threadIdx.x, g = lane >> 4, c = lane & 15;
    v8bf* wf = (v8bf*)ws;
    v8bf F;
    #pragma unroll
    for (int j = 0; j < 8; ++j) F[j] = (__bf16)proj_w[c*49 + g*8 + j];
    wf[0*64 + lane] = F;
    #pragma unroll
    for (int j = 0; j < 8; ++j) { int k = 32 + g*8 + j; F[j] = (k < 49) ? (__bf16)proj_w[c*49 + k] : (__bf16)0.f; }
    wf[1*64 + lane] = F;
    #pragma unroll
    for (int nt = 0; nt < 3; ++nt) {
        #pragma unroll
        for (int j = 0; j < 8; ++j) { int k = g*8 + j; F[j] = (k < 16) ? (__bf16)in_proj_w[(nt*16 + c)*16 + k] : (__bf16)0.f; }
        wf[(2 + nt)*64 + lane] = F;
    }
    #pragma unroll
    for (int j = 0; j < 8; ++j) { int k = g*8 + j; F[j] = (k < 16) ? (__bf16)out_w[c*16 + k] : (__bf16)0.f; }
    wf[5*64 + lane] = F;
    #pragma unroll
    for (int nt = 0; nt < 2; ++nt) {
        #pragma unroll
        for (int j = 0; j < 8; ++j) { int k = g*8 + j; F[j] = (k < 16) ? (__bf16)lin1_w[(nt*16 + c)*16 + k] : (__bf16)0.f; }
        wf[(6 + nt)*64 + lane] = F;
    }
    #pragma unroll
    for (int j = 0; j < 8; ++j) F[j] = (__bf16)lin2_w[c*32 + g*8 + j];
    wf[8*64 + lane] = F;

    float* hb = ws + WS_HB;
    #pragma unroll
    for (int ww = 0; ww < 4; ++ww)
        #pragma unroll
        for (int r = 0; r < 4; ++r)
            hb[ww*256 + r*64 + lane] = proj_b[c] + pos[(ww*16 + g*4 + r)*16 + c];

    if (lane < 16) {
        float* ep = ws + WS_EP + lane*16;
        ep[0]  = in_proj_b[lane];      // q bias
        ep[1]  = in_proj_b[16 + lane]; // k bias
        ep[2]  = in_proj_b[32 + lane]; // v bias
        ep[3]  = out_b[lane];
        ep[4]  = ln1_g[lane];
        ep[5]  = ln1_b[lane];
        ep[6]  = lin1_b[lane];
        ep[7]  = lin1_b[16 + lane];
        ep[8]  = lin2_b[lane];
        ep[9]  = ln2_g[lane];
        ep[10] = ln2_b[lane];
        ep[11] = head_w[lane];
        ep[12] = 0.f; ep[13] = 0.f; ep[14] = 0.f; ep[15] = 0.f;
    }
}

__global__ __launch_bounds__(256, 7)
void tx_main(const float* __restrict__ x, const float* __restrict__ ws,
             const float* __restrict__ head_b, float* __restrict__ out)
{
    __shared__ __align__(16) short sm[SMTOT];
    const int tid   = threadIdx.x;
    const int w     = tid >> 6;
    const int lane  = tid & 63;
    const int g     = lane >> 4;
    const int c     = lane & 15;
    const int b     = blockIdx.x;
    const int myrow = w*16 + c;
    const int tok0  = w*16 + g*4;
    const int sw    = (c >> 2) & 3;          // XR row-block swizzle for my A-rows
    const v8bf* wf  = (const v8bf*)ws;
    const float4* ep4 = (const float4*)(ws + WS_EP);

    v8bf zfrag;
    #pragma unroll
    for (int j = 0; j < 8; ++j) zfrag[j] = (__bf16)0.f;

    // ---- stage x -> XR (swizzled block layout), coalesced float4 ----
    const float4* xb4 = (const float4*)(x + (size_t)b * 3136);
    #pragma unroll
    for (int i = 0; i < 3; ++i) {
        int idx = tid + i*256;
        float4 v = xb4[idx];
        float vv[4] = {v.x, v.y, v.z, v.w};
        int flat = idx*4;
        #pragma unroll
        for (int e = 0; e < 4; ++e) {
            int f = flat + e, row = f / 49, col = f - row*49;
            int cs = (((col >> 3) ^ ((row >> 2) & 3)) << 3) | (col & 7);
            sm[XR + row*XRS + cs] = f2bs(vv[e]);
        }
    }
    if (tid < 16) {
        int idx = 768 + tid;
        float4 v = xb4[idx];
        float vv[4] = {v.x, v.y, v.z, v.w};
        int flat = idx*4;
        #pragma unroll
        for (int e = 0; e < 4; ++e) {
            int f = flat + e, row = f / 49, col = f - row*49;
            int cs = (((col >> 3) ^ ((row >> 2) & 3)) << 3) | (col & 7);
            sm[XR + row*XRS + cs] = f2bs(vv[e]);
        }
    }
    // zero pad cols 49..63 of my rows (swizzled), zero HR cols 16..31
    #pragma unroll
    for (int j = 0; j < 4; ++j) {
        int col = 49 + g*4 + j;
        if (col < 64) {
            int cs = (((col >> 3) ^ sw) << 3) | (col & 7);
            sm[XR + myrow*XRS + cs] = 0;
        }
    }
    *(unsigned long long*)&sm[HR + myrow*HRS + 16 + g*4] = 0ull;
    __syncthreads();

    // ---- proj: h = x @ proj_w^T (+ prebaked proj_b+pos), fp32 C-layout ----
    v4f hC;
    {
        v8bf Bp0 = wf[0*64 + lane], Bp1 = wf[1*64 + lane];
        v8bf a0 = *(const v8bf*)&sm[XR + myrow*XRS + ((g ^ sw) << 3)];
        v8bf a1 = *(const v8bf*)&sm[XR + myrow*XRS + 32 + ((g ^ sw) << 3)];
        v4f z = {0.f, 0.f, 0.f, 0.f};
        hC = MFMA(a0, Bp0, z);
        hC = MFMA(a1, Bp1, hC);
        const float* hb = ws + WS_HB;
        #pragma unroll
        for (int r = 0; r < 4; ++r) hC[r] += hb[w*256 + r*64 + lane];
        #pragma unroll
        for (int r = 0; r < 4; ++r) sm[HR + (tok0 + r)*HRS + c] = f2bs(hC[r]);
    }
    LDS_ORDER();

    // ---- qkv = h @ in_proj_w^T + b ----
    {
        v8bf Bq0 = wf[2*64 + lane], Bq1 = wf[3*64 + lane], Bq2 = wf[4*64 + lane];
        v8bf a = *(const v8bf*)&sm[HR + myrow*HRS + g*8];
        v4f z = {0.f, 0.f, 0.f, 0.f};
        v4f qC = MFMA(a, Bq0, z);
        v4f kC = MFMA(a, Bq1, z);
        v4f vC = MFMA(a, Bq2, z);
        float4 e0 = ep4[c*4];
        #pragma unroll
        for (int r = 0; r < 4; ++r) {
            int tok = tok0 + r;
            sm[HR + tok*HRS + c]   = f2bs(qC[r] + e0.x);
            sm[KR + tok*KRS + c]   = f2bs(kC[r] + e0.y);
            sm[VTB + c*VTS + tok]  = f2bs(vC[r] + e0.z);
        }
    }
    __syncthreads();

    // ---- attention: scores->exp->P (swizzled XR rows, private) -> PV ----
    v4f ctxC0, ctxC1;
    {
        v8bf aq = *(const v8bf*)&sm[HR + myrow*HRS + g*8];  // cols 16..31 zero
        const float SC = 0.510069729f;   // log2(e)/sqrt(8); scores<<1, no max-sub
        #pragma unroll
        for (int hh = 0; hh < 2; ++hh) {
            v4f sC[4];
            #pragma unroll
            for (int tj = 0; tj < 4; ++tj) {
                v8bf bk = zfrag;
                if (g == hh) bk = *(const v8bf*)&sm[KR + (tj*16 + c)*KRS + g*8];
                v4f z = {0.f, 0.f, 0.f, 0.f};
                sC[tj] = MFMA(aq, bk, z);
            }
            #pragma unroll
            for (int tj = 0; tj < 4; ++tj) {
                int cl = ((((tj*2) + (c >> 3)) ^ g) << 3) | (c & 7);  // swizzled col
                #pragma unroll
                for (int r = 0; r < 4; ++r)
                    sm[XR + (tok0 + r)*XRS + cl] = f2bs(exp2f(sC[tj][r] * SC));
            }
            v8bf bv0 = zfrag, bv1 = zfrag;
            bool act  = (hh == 0) ? (c < 8) : (c >= 8);
            int  onec = (hh == 0) ? 8 : 7;
            if (act) {
                bv0 = *(const v8bf*)&sm[VTB + c*VTS + g*8];
                bv1 = *(const v8bf*)&sm[VTB + c*VTS + 32 + g*8];
            } else if (c == onec) {
                #pragma unroll
                for (int j = 0; j < 8; ++j) { bv0[j] = (__bf16)1.f; bv1[j] = (__bf16)1.f; }
            }
            LDS_ORDER();
            v4f acc = {0.f, 0.f, 0.f, 0.f};
            acc = MFMA(*(const v8bf*)&sm[XR + myrow*XRS + ((g ^ sw) << 3)],      bv0, acc);
            acc = MFMA(*(const v8bf*)&sm[XR + myrow*XRS + 32 + ((g ^ sw) << 3)], bv1, acc);
            if (hh) ctxC1 = acc; else ctxC0 = acc;
            LDS_ORDER();
        }
    }

    // ---- softmax normalize (l via shfl from ones-column) + ctx scatter ----
    {
        int src0 = (lane & 48) | 8;
        int src1 = (lane & 48) | 7;
        #pragma unroll
        for (int r = 0; r < 4; ++r) {
            float l0 = __shfl(ctxC0[r], src0, 64);
            float l1 = __shfl(ctxC1[r], src1, 64);
            float val = (c < 8) ? (ctxC0[r] / l0) : (ctxC1[r] / l1);
            sm[HR + (tok0 + r)*HRS + c] = f2bs(val);
        }
    }
    LDS_ORDER();

    // ---- out-proj + residual + LN1 (C-layout butterflies) ----
    v4f hln;
    {
        v8bf Bo = wf[5*64 + lane];
        v8bf a = *(const v8bf*)&sm[HR + myrow*HRS + g*8];
        v4f z = {0.f, 0.f, 0.f, 0.f};
        v4f oC = MFMA(a, Bo, z);
        float4 e0 = ep4[c*4];
        float4 e1 = ep4[c*4 + 1];
        v4f hn;
        #pragma unroll
        for (int r = 0; r < 4; ++r) hn[r] = hC[r] + oC[r] + e0.w;
        v4f s = hn;
        #pragma unroll
        for (int m = 1; m < 16; m <<= 1)
            #pragma unroll
            for (int r = 0; r < 4; ++r) s[r] += __shfl_xor(s[r], m, 64);
        v4f t, vs;
        #pragma unroll
        for (int r = 0; r < 4; ++r) { t[r] = hn[r] - s[r]*0.0625f; vs[r] = t[r]*t[r]; }
        #pragma unroll
        for (int m = 1; m < 16; m <<= 1)
            #pragma unroll
            for (int r = 0; r < 4; ++r) vs[r] += __shfl_xor(vs[r], m, 64);
        #pragma unroll
        for (int r = 0; r < 4; ++r) {
            float is = rsqrtf(vs[r]*0.0625f + 1e-5f);
            hln[r] = t[r]*is*e1.x + e1.y;
            sm[HR + (tok0 + r)*HRS + c] = f2bs(hln[r]);
        }
    }
    LDS_ORDER();

    // ---- FFN: lin1(+bias,relu) -> lin2 (K=32) ----
    v4f o2;
    {
        v8bf Bl10 = wf[6*64 + lane], Bl11 = wf[7*64 + lane], Bl2 = wf[8*64 + lane];
        v8bf a = *(const v8bf*)&sm[HR + myrow*HRS + g*8];
        v4f z = {0.f, 0.f, 0.f, 0.f};
        v4f f0 = MFMA(a, Bl10, z);
        v4f f1 = MFMA(a, Bl11, z);
        float4 e1 = ep4[c*4 + 1];
        #pragma unroll
        for (int r = 0; r < 4; ++r) {
            int tok = tok0 + r;
            sm[HR + tok*HRS + c]      = f2bs(fmaxf(f0[r] + e1.z, 0.f));
            sm[HR + tok*HRS + 16 + c] = f2bs(fmaxf(f1[r] + e1.w, 0.f));
        }
        LDS_ORDER();
        v8bf a2 = *(const v8bf*)&sm[HR + myrow*HRS + g*8];
        o2 = MFMA(a2, Bl2, z);
    }

    // ---- +lin2_b, residual, LN2, head dot; wave + cross-wave reduce ----
    float part = 0.f;
    {
        float4 e2 = ep4[c*4 + 2];
        v4f hn;
        #pragma unroll
        for (int r = 0; r < 4; ++r) hn[r] = hln[r] + o2[r] + e2.x;
        v4f s = hn;
        #pragma unroll
        for (int m = 1; m < 16; m <<= 1)
            #pragma unroll
            for (int r = 0; r < 4; ++r) s[r] += __shfl_xor(s[r], m, 64);
        v4f t, vs;
        #pragma unroll
        for (int r = 0; r < 4; ++r) { t[r] = hn[r] - s[r]*0.0625f; vs[r] = t[r]*t[r]; }
        #pragma unroll
        for (int m = 1; m < 16; m <<= 1)
            #pragma unroll
            for (int r = 0; r < 4; ++r) vs[r] += __shfl_xor(vs[r], m, 64);
        #pragma unroll
        for (int r = 0; r < 4; ++r) {
            float is = rsqrtf(vs[r]*0.0625f + 1e-5f);
            float h3 = t[r]*is*e2.y + e2.z;
            part = fmaf(h3, e2.w, part);
        }
    }
    #pragma unroll
    for (int m = 1; m < 64; m <<= 1) part += __shfl_xor(part, m, 64);
    float* fred = (float*)&sm[RED];
    if (lane == 0) fred[w] = part;
    __syncthreads();
    if (tid == 0)
        out[b] = (fred[0] + fred[1] + fred[2] + fred[3]) * (1.f/64.f) + head_b[0];
}

extern "C" void kernel_launch(void* const* d_in, const int* in_sizes, int n_in,
                              void* d_out, int out_size, void* d_ws, size_t ws_size,
                              hipStream_t stream) {
    const float* x         = (const float*)d_in[0];
    const float* proj_w    = (const float*)d_in[1];
    const float* proj_b    = (const float*)d_in[2];
    const float* pos       = (const float*)d_in[3];
    const float* in_proj_w = (const float*)d_in[4];
    const float* in_proj_b = (const float*)d_in[5];
    const float* out_w     = (const float*)d_in[6];
    const float* out_b     = (const float*)d_in[7];
    const float* ln1_g     = (const float*)d_in[8];
    const float* ln1_b     = (const float*)d_in[9];
    const float* lin1_w    = (const float*)d_in[10];
    const float* lin1_b    = (const float*)d_in[11];
    const float* lin2_w    = (const float*)d_in[12];
    const float* lin2_b    = (const float*)d_in[13];
    const float* ln2_g     = (const float*)d_in[14];
    const float* ln2_b     = (const float*)d_in[15];
    const float* head_w    = (const float*)d_in[16];
    const float* head_b    = (const float*)d_in[17];
    float* ws = (float*)d_ws;

    tx_prep<<<1, 64, 0, stream>>>(proj_w, proj_b, pos, in_proj_w, in_proj_b,
                                  out_w, out_b, ln1_g, ln1_b, lin1_w, lin1_b,
                                  lin2_w, lin2_b, ln2_g, ln2_b, head_w, ws);
    tx_main<<<16384, 256, 0, stream>>>(x, ws, head_b, (float*)d_out);
}